// Round 5
// baseline (329.121 us; speedup 1.0000x reference)
//
#include <hip/hip_runtime.h>
#include <math.h>

#define TWO_PI 6.28318530717958647692f
#define SCALE_INV_SQRT_D 0.08838834764831844f   // 1/sqrt(128)

#define NQ 65536
#define NV 131072

typedef __attribute__((ext_vector_type(8))) short s16x8;
typedef __attribute__((ext_vector_type(4))) float f32x4;

__device__ __forceinline__ unsigned short f2bf(float f) {
    unsigned int u = __builtin_bit_cast(unsigned int, f);
    u += 0x7fffu + ((u >> 16) & 1u);          // round-to-nearest-even
    return (unsigned short)(u >> 16);
}
__device__ __forceinline__ float bf2f(unsigned short s) {
    return __builtin_bit_cast(float, (unsigned)s << 16);
}

// k-slot permutation of the D-fragment layout (HW-verified in R4):
// slot (g,i) of a packed-D A-frag holds k = ks*32 + (i>=4)*16 + g*4 + (i&3).
__device__ __forceinline__ int kperm(int kk) {
    int i = kk & 7, gg = (kk >> 3) & 3, ks = kk >> 5;
    return (ks << 5) + ((i & 4) << 2) + (gg << 2) + (i & 3);
}

// ---------------------------------------------------------------------------
// prep: weights -> bf16, transposed to [N][K]. W2-like matrices (consumed as
// A-frags built from GEMM1 D-frags) get the k-slot permutation baked in.
// wbuf (ushort): qw1t[32768] qw2tp[32768] vw1t[32768] vw2tp[32768]
//                sewrt[16384] sewetp[16384]
// ---------------------------------------------------------------------------
__global__ __launch_bounds__(256) void prep_kernel(
    const float* __restrict__ qw1, const float* __restrict__ qw2,
    const float* __restrict__ vw1, const float* __restrict__ vw2,
    const float* __restrict__ sewr, const float* __restrict__ sewe,
    unsigned short* __restrict__ wbuf)
{
    int i = blockIdx.x * 256 + threadIdx.x;   // 163840 total
    float v;
    if (i < 32768)        { int li = i;          int n = li >> 7, k = li & 127;          v = qw1[k * 256 + n]; }
    else if (i < 65536)   { int li = i - 32768;  int n = li >> 8, k = kperm(li & 255);   v = qw2[k * 128 + n]; }
    else if (i < 98304)   { int li = i - 65536;  int n = li >> 7, k = li & 127;          v = vw1[k * 256 + n]; }
    else if (i < 131072)  { int li = i - 98304;  int n = li >> 8, k = kperm(li & 255);   v = vw2[k * 128 + n]; }
    else if (i < 147456)  { int li = i - 131072; int n = li >> 7, k = li & 127;          v = sewr[k * 128 + n]; }
    else                  { int li = i - 147456; int n = li >> 7, k = kperm(li & 127);   v = sewe[k * 128 + n]; }
    wbuf[i] = f2bf(v);
}

// ---------------------------------------------------------------------------
// mlp_kernel v3: ZERO LDS, ZERO barriers. 4 independent waves/block, each
// wave owns 16 samples end-to-end, everything register-resident.
//   GEMM1 computes h^T tiles: mfma(A=W1^T-frag, B=pe^T-frag)
//     -> D: sample=lane&15, hidden=(lane>>4)*4+reg
//   relu+bias+pack pairs of tiles -> s16x8 = GEMM2 A-frags (kperm'd W2).
//   pe B-frags computed fully per-lane (lane (g,r16) = sample r16,
//   dims ks*32+g*8..+7), sin/cos via HW v_sin/v_cos in revolutions.
// ---------------------------------------------------------------------------
template<bool GATE>
__global__ __launch_bounds__(256) void mlp_kernel(
    const float* __restrict__ ref_pts,
    const int*   __restrict__ ctr_coor,
    const float* __restrict__ ctr_feat,
    const unsigned short* __restrict__ w1t,   // [256][128]
    const float* __restrict__ b1,
    const unsigned short* __restrict__ w2tp,  // [128][256] k-permuted
    const float* __restrict__ b2,
    const unsigned short* __restrict__ sewrt, // [128][128]
    const float* __restrict__ sebr,
    const unsigned short* __restrict__ sewetp,// [128][128] k-permuted
    const float* __restrict__ sebe,
    unsigned short* __restrict__ outb)        // rows x 128 bf16
{
    const int t    = threadIdx.x;
    const int lane = t & 63;
    const int wid  = t >> 6;
    const int r16  = lane & 15;
    const int g    = lane >> 4;
    const int row0w = blockIdx.x * 64 + wid * 16;
    const int samp  = row0w + r16;

    // ---- normalized position of this lane's sample (revolutions in [0,1])
    float xx, yy;
    if (GATE) {
        xx = ((float)ctr_coor[samp * 3 + 1] + 0.5f) * 0.2f;
        yy = ((float)ctr_coor[samp * 3 + 2] + 0.5f) * 0.2f;
    } else {
        xx = ref_pts[samp * 3 + 1];
        yy = ref_pts[samp * 3 + 2];
    }
    const float pnx = (xx + 51.2f) * (1.0f / 102.4f);
    const float pny = (yy + 51.2f) * (1.0f / 102.4f);

    // ================= SE gate path (V only) =================
    f32x4 gacc[8];
    if (GATE) {
        // feat B-frags: lane (g,r16) loads feat[r16][ks*32+g*8 .. +7]
        s16x8 fb[4];
        #pragma unroll
        for (int ks = 0; ks < 4; ++ks) {
            const float* src = ctr_feat + (size_t)samp * 128 + ks * 32 + g * 8;
            f32x4 v0 = *(const f32x4*)(src);
            f32x4 v1 = *(const f32x4*)(src + 4);
            s16x8 pk;
            #pragma unroll
            for (int e = 0; e < 4; ++e) {
                pk[e]     = (short)f2bf(v0[e]);
                pk[4 + e] = (short)f2bf(v1[e]);
            }
            fb[ks] = pk;
        }
        // SE1: g1^T tiles -> packed A-frags ga[4]
        s16x8 ga[4];
        #pragma unroll
        for (int u = 0; u < 4; ++u) {
            f32x4 a0 = (f32x4)0.f, a1 = (f32x4)0.f;
            #pragma unroll
            for (int ks = 0; ks < 4; ++ks) {
                s16x8 w0 = *(const s16x8*)(sewrt + ((2 * u) * 16 + r16) * 128 + ks * 32 + g * 8);
                s16x8 w1 = *(const s16x8*)(sewrt + ((2 * u + 1) * 16 + r16) * 128 + ks * 32 + g * 8);
                a0 = __builtin_amdgcn_mfma_f32_16x16x32_bf16(w0, fb[ks], a0, 0, 0, 0);
                a1 = __builtin_amdgcn_mfma_f32_16x16x32_bf16(w1, fb[ks], a1, 0, 0, 0);
            }
            f32x4 bb0 = *(const f32x4*)(sebr + 32 * u + g * 4);
            f32x4 bb1 = *(const f32x4*)(sebr + 32 * u + 16 + g * 4);
            s16x8 pk;
            #pragma unroll
            for (int r = 0; r < 4; ++r) {
                pk[r]     = (short)f2bf(fmaxf(a0[r] + bb0[r], 0.f));
                pk[4 + r] = (short)f2bf(fmaxf(a1[r] + bb1[r], 0.f));
            }
            ga[u] = pk;
        }
        // SE2: gacc = g1 @ se_we (kperm'd B)
        #pragma unroll
        for (int n = 0; n < 8; ++n) gacc[n] = (f32x4)0.f;
        #pragma unroll
        for (int n = 0; n < 8; ++n)
            #pragma unroll
            for (int u = 0; u < 4; ++u) {
                s16x8 b = *(const s16x8*)(sewetp + (n * 16 + r16) * 128 + u * 32 + g * 8);
                gacc[n] = __builtin_amdgcn_mfma_f32_16x16x32_bf16(ga[u], b, gacc[n], 0, 0, 0);
            }
    }

    // ================= positional-embedding MLP =================
    // pe B-frags: computed entirely in-lane.
    s16x8 ape[4];
    #pragma unroll
    for (int ks = 0; ks < 4; ++ks) {
        const float p = (ks < 2) ? pny : pnx;
        s16x8 pk;
        #pragma unroll
        for (int j = 0; j < 4; ++j) {
            float fr  = (float)(ks * 16 + g * 4 + j);
            float rev = p * __builtin_exp2f(fr * -0.41524101186092029f); // 10000^(-f/32)
            float sn, cs;
            asm("v_sin_f32 %0, %1" : "=v"(sn) : "v"(rev));
            asm("v_cos_f32 %0, %1" : "=v"(cs) : "v"(rev));
            pk[2 * j]     = (short)f2bf(sn);
            pk[2 * j + 1] = (short)f2bf(cs);
        }
        ape[ks] = pk;
    }

    // GEMM1: h^T tiles -> packed GEMM2 A-frags ha[8]
    s16x8 ha[8];
    #pragma unroll
    for (int u = 0; u < 8; ++u) {
        f32x4 a0 = (f32x4)0.f, a1 = (f32x4)0.f;
        #pragma unroll
        for (int ks = 0; ks < 4; ++ks) {
            s16x8 w0 = *(const s16x8*)(w1t + ((2 * u) * 16 + r16) * 128 + ks * 32 + g * 8);
            s16x8 w1 = *(const s16x8*)(w1t + ((2 * u + 1) * 16 + r16) * 128 + ks * 32 + g * 8);
            a0 = __builtin_amdgcn_mfma_f32_16x16x32_bf16(w0, ape[ks], a0, 0, 0, 0);
            a1 = __builtin_amdgcn_mfma_f32_16x16x32_bf16(w1, ape[ks], a1, 0, 0, 0);
        }
        f32x4 bb0 = *(const f32x4*)(b1 + 32 * u + g * 4);
        f32x4 bb1 = *(const f32x4*)(b1 + 32 * u + 16 + g * 4);
        s16x8 pk;
        #pragma unroll
        for (int r = 0; r < 4; ++r) {
            pk[r]     = (short)f2bf(fmaxf(a0[r] + bb0[r], 0.f));
            pk[4 + r] = (short)f2bf(fmaxf(a1[r] + bb1[r], 0.f));
        }
        ha[u] = pk;
    }

    // GEMM2: c2 = h @ W2 (kperm'd B), K=256
    f32x4 c2[8];
    #pragma unroll
    for (int n = 0; n < 8; ++n) c2[n] = (f32x4)0.f;
    #pragma unroll
    for (int n = 0; n < 8; ++n)
        #pragma unroll
        for (int u = 0; u < 8; ++u) {
            s16x8 b = *(const s16x8*)(w2tp + (n * 16 + r16) * 256 + u * 32 + g * 8);
            c2[n] = __builtin_amdgcn_mfma_f32_16x16x32_bf16(ha[u], b, c2[n], 0, 0, 0);
        }

    // ---- epilogue: D layout col=n*16+r16, sample=row0w+g*4+r
    #pragma unroll
    for (int n = 0; n < 8; ++n) {
        const int col = n * 16 + r16;
        const float b2v = b2[col];
        if (GATE) {
            const float bev = sebe[col];
            #pragma unroll
            for (int r = 0; r < 4; ++r) {
                float gate = 1.0f / (1.0f + __expf(-(gacc[n][r] + bev)));
                outb[(size_t)(row0w + g * 4 + r) * 128 + col] = f2bf((c2[n][r] + b2v) * gate);
            }
        } else {
            #pragma unroll
            for (int r = 0; r < 4; ++r)
                outb[(size_t)(row0w + g * 4 + r) * 128 + col] = f2bf(c2[n][r] + b2v);
        }
    }
}

// ---------------------------------------------------------------------------
// attention: one wave per query; qpos/vposg bf16, feat f32.
// ---------------------------------------------------------------------------
__global__ __launch_bounds__(256) void attn_kernel(
    const float* __restrict__ ref_pts,
    const unsigned short* __restrict__ qpos,
    const unsigned short* __restrict__ vposg,
    const float* __restrict__ ctr_feat,
    float* __restrict__ out)
{
    const int lane = threadIdx.x & 63;
    const int qi   = blockIdx.x * 4 + (threadIdx.x >> 6);

    const int   b = (int)ref_pts[qi * 3 + 0];
    const float x = ref_pts[qi * 3 + 1];
    const float y = ref_pts[qi * 3 + 2];
    const int xi = (int)(floorf(x / 0.2f) * 0.5f + 128.0f);
    const int yi = (int)(floorf(y / 0.2f) * 0.5f + 128.0f);

    const unsigned qp = *(const unsigned*)(qpos + (size_t)qi * 128 + lane * 2);
    const float qx = bf2f((unsigned short)(qp & 0xffffu));
    const float qy = bf2f((unsigned short)(qp >> 16));

    float  sc[9];
    float2 fv[9];
    #pragma unroll
    for (int n = 0; n < 9; ++n) {
        const int nx = xi + n / 3 - 1;
        const int ny = yi + n % 3 - 1;
        const bool valid = ((unsigned)nx < 256u) && ((unsigned)ny < 256u);
        float  s = 0.f;
        float2 f = {0.f, 0.f};
        if (valid) {
            const int idx = (b << 16) + (nx << 8) + ny;
            const unsigned vp = *(const unsigned*)(vposg + (size_t)idx * 128 + lane * 2);
            f = *(const float2*)(ctr_feat + (size_t)idx * 128 + lane * 2);
            s = qx * bf2f((unsigned short)(vp & 0xffffu)) + qy * bf2f((unsigned short)(vp >> 16));
        }
        sc[n] = s;
        fv[n] = f;
    }

    #pragma unroll
    for (int off = 32; off > 0; off >>= 1) {
        #pragma unroll
        for (int n = 0; n < 9; ++n)
            sc[n] += __shfl_xor(sc[n], off, 64);
    }

    float m = -1e30f;
    #pragma unroll
    for (int n = 0; n < 9; ++n) {
        sc[n] *= SCALE_INV_SQRT_D;
        m = fmaxf(m, sc[n]);
    }
    float e[9], denom = 0.f;
    #pragma unroll
    for (int n = 0; n < 9; ++n) {
        e[n] = __expf(sc[n] - m);
        denom += e[n];
    }
    const float inv = 1.0f / denom;

    float2 o = {0.f, 0.f};
    #pragma unroll
    for (int n = 0; n < 9; ++n) {
        const float w = e[n] * inv;
        o.x += w * fv[n].x;
        o.y += w * fv[n].y;
    }
    *(float2*)(out + (size_t)qi * 128 + lane * 2) = o;
}

extern "C" void kernel_launch(void* const* d_in, const int* in_sizes, int n_in,
                              void* d_out, int out_size, void* d_ws, size_t ws_size,
                              hipStream_t stream) {
    const float* ref_pts  = (const float*)d_in[0];
    const int*   ctr_coor = (const int*)d_in[1];
    const float* ctr_feat = (const float*)d_in[2];
    const float* q_w1 = (const float*)d_in[3];
    const float* q_b1 = (const float*)d_in[4];
    const float* q_w2 = (const float*)d_in[5];
    const float* q_b2 = (const float*)d_in[6];
    const float* v_w1 = (const float*)d_in[7];
    const float* v_b1 = (const float*)d_in[8];
    const float* v_w2 = (const float*)d_in[9];
    const float* v_b2 = (const float*)d_in[10];
    const float* se_wr = (const float*)d_in[11];
    const float* se_br = (const float*)d_in[12];
    const float* se_we = (const float*)d_in[13];
    const float* se_be = (const float*)d_in[14];

    unsigned short* wbuf  = (unsigned short*)d_ws;                  // 163840
    unsigned short* vposg = wbuf + 163840;                          // V*128 bf16
    unsigned short* qposb = vposg + (size_t)NV * 128;               // Q*128 bf16

    const unsigned short* qw1t   = wbuf;
    const unsigned short* qw2tp  = wbuf + 32768;
    const unsigned short* vw1t   = wbuf + 65536;
    const unsigned short* vw2tp  = wbuf + 98304;
    const unsigned short* sewrt  = wbuf + 131072;
    const unsigned short* sewetp = wbuf + 147456;

    prep_kernel<<<640, 256, 0, stream>>>(q_w1, q_w2, v_w1, v_w2, se_wr, se_we, wbuf);

    mlp_kernel<false><<<NQ / 64, 256, 0, stream>>>(
        ref_pts, nullptr, nullptr,
        qw1t, q_b1, qw2tp, q_b2,
        nullptr, nullptr, nullptr, nullptr, qposb);

    mlp_kernel<true><<<NV / 64, 256, 0, stream>>>(
        nullptr, ctr_coor, ctr_feat,
        vw1t, v_b1, vw2tp, v_b2,
        sewrt, se_br, sewetp, se_be, vposg);

    attn_kernel<<<NQ / 4, 256, 0, stream>>>(
        ref_pts, qposb, vposg, ctr_feat, (float*)d_out);
}

// Round 6
// 219.518 us; speedup vs baseline: 1.4993x; 1.4993x over previous
//
#include <hip/hip_runtime.h>
#include <math.h>

#define SCALE_INV_SQRT_D 0.08838834764831844f   // 1/sqrt(128)

#define NQ 65536
#define NV 131072

typedef __attribute__((ext_vector_type(8))) short s16x8;
typedef __attribute__((ext_vector_type(4))) float f32x4;

__device__ __forceinline__ unsigned short f2bf(float f) {
    unsigned int u = __builtin_bit_cast(unsigned int, f);
    u += 0x7fffu + ((u >> 16) & 1u);          // round-to-nearest-even
    return (unsigned short)(u >> 16);
}
__device__ __forceinline__ float bf2f(unsigned short s) {
    return __builtin_bit_cast(float, (unsigned)s << 16);
}

// k-slot permutation of the D-fragment layout (HW-verified in R4/R5):
// slot (g,i) of a packed-D A-frag holds k = ks*32 + (i>=4)*16 + g*4 + (i&3).
__device__ __forceinline__ int kperm(int kk) {
    int i = kk & 7, gg = (kk >> 3) & 3, ks = kk >> 5;
    return (ks << 5) + ((i & 4) << 2) + (gg << 2) + (i & 3);
}

// ---------------------------------------------------------------------------
// prep: weights -> bf16, transposed to [N][K]; W2-like get kperm baked in.
// wbuf (ushort): qw1t[32768] qw2tp[32768] vw1t[32768] vw2tp[32768]
//                sewrt[16384] sewetp[16384]
// ---------------------------------------------------------------------------
__global__ __launch_bounds__(256) void prep_kernel(
    const float* __restrict__ qw1, const float* __restrict__ qw2,
    const float* __restrict__ vw1, const float* __restrict__ vw2,
    const float* __restrict__ sewr, const float* __restrict__ sewe,
    unsigned short* __restrict__ wbuf)
{
    int i = blockIdx.x * 256 + threadIdx.x;   // 163840 total
    float v;
    if (i < 32768)        { int li = i;          int n = li >> 7, k = li & 127;          v = qw1[k * 256 + n]; }
    else if (i < 65536)   { int li = i - 32768;  int n = li >> 8, k = kperm(li & 255);   v = qw2[k * 128 + n]; }
    else if (i < 98304)   { int li = i - 65536;  int n = li >> 7, k = li & 127;          v = vw1[k * 256 + n]; }
    else if (i < 131072)  { int li = i - 98304;  int n = li >> 8, k = kperm(li & 255);   v = vw2[k * 128 + n]; }
    else if (i < 147456)  { int li = i - 131072; int n = li >> 7, k = li & 127;          v = sewr[k * 128 + n]; }
    else                  { int li = i - 147456; int n = li >> 7, k = kperm(li & 127);   v = sewe[k * 128 + n]; }
    wbuf[i] = f2bf(v);
}

// ---------------------------------------------------------------------------
// se_gate: gate = sigmoid(relu(feat@se_wr+br)@se_we+be), stored PACKED in
// D-frag layout: gate_p[tile16*2048 + col*16 + (g*4+r)] (bf16).
// Weights staged once in 64KB LDS (XOR-swizzled). One 32-sample tile/wave.
// ---------------------------------------------------------------------------
__global__ __launch_bounds__(512) void se_gate_kernel(
    const float* __restrict__ ctr_feat,
    const unsigned short* __restrict__ sewrt,  // [128][128]
    const float* __restrict__ sebr,
    const unsigned short* __restrict__ sewetp, // [128][128] k-permuted
    const float* __restrict__ sebe,
    unsigned short* __restrict__ gate_p)
{
    __shared__ __attribute__((aligned(16))) char s_w[65536];
    const int t = threadIdx.x;
    // stage sewrt -> [0,32768), sewetp -> [32768,65536); swizzle ^(row&7)<<4
    for (int c = t; c < 4096; c += 512) {
        int b  = c * 16;
        int lb = b & 32767;
        int row = lb >> 8;                       // both stride 256B
        int dst = (b & 32768) + (lb ^ ((row & 7) << 4));
        const unsigned short* src = (b < 32768) ? (sewrt + lb / 2) : (sewetp + (lb / 2));
        *(s16x8*)(s_w + dst) = *(const s16x8*)src;
    }
    __syncthreads();

    const int lane = t & 63, wid = t >> 6;
    const int r16 = lane & 15, g = lane >> 4;
    const int swz = (r16 & 7) << 4;
    const int w  = blockIdx.x * 8 + wid;         // tile32 id (4096 total)
    const int s0 = w * 32;

    // feat B-frags for both 16-groups
    s16x8 fb[2][4];
    #pragma unroll
    for (int gr = 0; gr < 2; ++gr) {
        const int samp = s0 + gr * 16 + r16;
        #pragma unroll
        for (int ks = 0; ks < 4; ++ks) {
            const float* src = ctr_feat + (size_t)samp * 128 + ks * 32 + g * 8;
            f32x4 v0 = *(const f32x4*)(src);
            f32x4 v1 = *(const f32x4*)(src + 4);
            s16x8 pk;
            #pragma unroll
            for (int e = 0; e < 4; ++e) {
                pk[e]     = (short)f2bf(v0[e]);
                pk[4 + e] = (short)f2bf(v1[e]);
            }
            fb[gr][ks] = pk;
        }
    }
    // SE1: g1^T tiles -> packed A-frags
    s16x8 ga[2][4];
    #pragma unroll
    for (int u = 0; u < 4; ++u) {
        f32x4 a0[2], a1[2];
        #pragma unroll
        for (int gr = 0; gr < 2; ++gr) { a0[gr] = (f32x4)0.f; a1[gr] = (f32x4)0.f; }
        #pragma unroll
        for (int ks = 0; ks < 4; ++ks) {
            s16x8 w0 = *(const s16x8*)(s_w + ((((2 * u) * 16 + r16) * 256 + ks * 64 + g * 16) ^ swz));
            s16x8 w1 = *(const s16x8*)(s_w + ((((2 * u + 1) * 16 + r16) * 256 + ks * 64 + g * 16) ^ swz));
            #pragma unroll
            for (int gr = 0; gr < 2; ++gr) {
                a0[gr] = __builtin_amdgcn_mfma_f32_16x16x32_bf16(w0, fb[gr][ks], a0[gr], 0, 0, 0);
                a1[gr] = __builtin_amdgcn_mfma_f32_16x16x32_bf16(w1, fb[gr][ks], a1[gr], 0, 0, 0);
            }
        }
        f32x4 bb0 = *(const f32x4*)(sebr + 32 * u + g * 4);
        f32x4 bb1 = *(const f32x4*)(sebr + 32 * u + 16 + g * 4);
        #pragma unroll
        for (int gr = 0; gr < 2; ++gr) {
            s16x8 pk;
            #pragma unroll
            for (int r = 0; r < 4; ++r) {
                pk[r]     = (short)f2bf(fmaxf(a0[gr][r] + bb0[r], 0.f));
                pk[4 + r] = (short)f2bf(fmaxf(a1[gr][r] + bb1[r], 0.f));
            }
            ga[gr][u] = pk;
        }
    }
    // SE2 + sigmoid + packed store
    #pragma unroll
    for (int n = 0; n < 8; ++n) {
        f32x4 acc[2] = {(f32x4)0.f, (f32x4)0.f};
        #pragma unroll
        for (int u = 0; u < 4; ++u) {
            s16x8 b = *(const s16x8*)(s_w + 32768 + (((n * 16 + r16) * 256 + u * 64 + g * 16) ^ swz));
            #pragma unroll
            for (int gr = 0; gr < 2; ++gr)
                acc[gr] = __builtin_amdgcn_mfma_f32_16x16x32_bf16(ga[gr][u], b, acc[gr], 0, 0, 0);
        }
        const int col = n * 16 + r16;
        const float bev = sebe[col];
        #pragma unroll
        for (int gr = 0; gr < 2; ++gr) {
            unsigned short pk[4];
            #pragma unroll
            for (int r = 0; r < 4; ++r)
                pk[r] = f2bf(1.0f / (1.0f + __expf(-(acc[gr][r] + bev))));
            *(unsigned long long*)(gate_p + (size_t)(2 * w + gr) * 2048 + col * 16 + g * 4)
                = *(const unsigned long long*)pk;
        }
    }
}

// ---------------------------------------------------------------------------
// pe_mlp: MLP(pos2posemb2d(p)) with weights staged in 128KB LDS.
// M_tile=32/wave (two 16-groups share every weight-frag read).
// GATE: multiply by pre-packed gate (same D-frag layout -> coalesced 8B load).
// ---------------------------------------------------------------------------
template<bool GATE>
__global__ __launch_bounds__(512) void pe_mlp_kernel(
    const float* __restrict__ ref_pts,
    const int*   __restrict__ ctr_coor,
    const unsigned short* __restrict__ w1t,   // [256][128]
    const float* __restrict__ b1,
    const unsigned short* __restrict__ w2tp,  // [128][256] k-permuted
    const float* __restrict__ b2,
    const unsigned short* __restrict__ gate_p,
    unsigned short* __restrict__ outb,        // rows x 128 bf16
    int ntile32)
{
    __shared__ __attribute__((aligned(16))) char s_w[131072];
    const int t = threadIdx.x;
    // stage w1t [256][128] (stride 256B) -> [0,64K); w2tp [128][256] (512B) -> [64K,128K)
    for (int c = t; c < 8192; c += 512) {
        int b = c * 16;
        if (b < 65536) {
            int row = b >> 8;
            *(s16x8*)(s_w + (b ^ ((row & 7) << 4))) = *(const s16x8*)(w1t + b / 2);
        } else {
            int lb = b - 65536;
            int row = lb >> 9;
            *(s16x8*)(s_w + 65536 + (lb ^ ((row & 7) << 4))) = *(const s16x8*)(w2tp + lb / 2);
        }
    }
    __syncthreads();

    const int lane = t & 63, wid = t >> 6;
    const int r16 = lane & 15, g = lane >> 4;
    const int swz = (r16 & 7) << 4;

    for (int w = blockIdx.x * 8 + wid; w < ntile32; w += gridDim.x * 8) {
        const int s0 = w * 32;

        // pe B-frags, fully in-lane
        s16x8 ape[2][4];
        #pragma unroll
        for (int gr = 0; gr < 2; ++gr) {
            const int samp = s0 + gr * 16 + r16;
            float xx, yy;
            if (GATE) {
                xx = ((float)ctr_coor[samp * 3 + 1] + 0.5f) * 0.2f;
                yy = ((float)ctr_coor[samp * 3 + 2] + 0.5f) * 0.2f;
            } else {
                xx = ref_pts[samp * 3 + 1];
                yy = ref_pts[samp * 3 + 2];
            }
            const float pnx = (xx + 51.2f) * (1.0f / 102.4f);   // revolutions
            const float pny = (yy + 51.2f) * (1.0f / 102.4f);
            #pragma unroll
            for (int ks = 0; ks < 4; ++ks) {
                const float p = (ks < 2) ? pny : pnx;
                s16x8 pk;
                #pragma unroll
                for (int j = 0; j < 4; ++j) {
                    float fr  = (float)(ks * 16 + g * 4 + j);
                    float rev = p * __builtin_exp2f(fr * -0.41524101186092029f);
                    float sn, cs;
                    asm("v_sin_f32 %0, %1" : "=v"(sn) : "v"(rev));
                    asm("v_cos_f32 %0, %1" : "=v"(cs) : "v"(rev));
                    pk[2 * j]     = (short)f2bf(sn);
                    pk[2 * j + 1] = (short)f2bf(cs);
                }
                ape[gr][ks] = pk;
            }
        }

        // GEMM1: h^T tiles -> packed GEMM2 A-frags
        s16x8 ha[2][8];
        #pragma unroll
        for (int u = 0; u < 8; ++u) {
            f32x4 a0[2], a1[2];
            #pragma unroll
            for (int gr = 0; gr < 2; ++gr) { a0[gr] = (f32x4)0.f; a1[gr] = (f32x4)0.f; }
            #pragma unroll
            for (int ks = 0; ks < 4; ++ks) {
                s16x8 w0 = *(const s16x8*)(s_w + ((((2 * u) * 16 + r16) * 256 + ks * 64 + g * 16) ^ swz));
                s16x8 w1 = *(const s16x8*)(s_w + ((((2 * u + 1) * 16 + r16) * 256 + ks * 64 + g * 16) ^ swz));
                #pragma unroll
                for (int gr = 0; gr < 2; ++gr) {
                    a0[gr] = __builtin_amdgcn_mfma_f32_16x16x32_bf16(w0, ape[gr][ks], a0[gr], 0, 0, 0);
                    a1[gr] = __builtin_amdgcn_mfma_f32_16x16x32_bf16(w1, ape[gr][ks], a1[gr], 0, 0, 0);
                }
            }
            f32x4 bb0 = *(const f32x4*)(b1 + 32 * u + g * 4);
            f32x4 bb1 = *(const f32x4*)(b1 + 32 * u + 16 + g * 4);
            #pragma unroll
            for (int gr = 0; gr < 2; ++gr) {
                s16x8 pk;
                #pragma unroll
                for (int r = 0; r < 4; ++r) {
                    pk[r]     = (short)f2bf(fmaxf(a0[gr][r] + bb0[r], 0.f));
                    pk[4 + r] = (short)f2bf(fmaxf(a1[gr][r] + bb1[r], 0.f));
                }
                ha[gr][u] = pk;
            }
        }

        // GEMM2 (K=256) + epilogue
        #pragma unroll
        for (int n = 0; n < 8; ++n) {
            f32x4 c2[2] = {(f32x4)0.f, (f32x4)0.f};
            #pragma unroll
            for (int u = 0; u < 8; ++u) {
                s16x8 b = *(const s16x8*)(s_w + 65536 + (((n * 16 + r16) * 512 + u * 64 + g * 16) ^ swz));
                #pragma unroll
                for (int gr = 0; gr < 2; ++gr)
                    c2[gr] = __builtin_amdgcn_mfma_f32_16x16x32_bf16(ha[gr][u], b, c2[gr], 0, 0, 0);
            }
            const int col = n * 16 + r16;
            const float b2v = b2[col];
            #pragma unroll
            for (int gr = 0; gr < 2; ++gr) {
                unsigned short gk[4];
                if (GATE) {
                    *(unsigned long long*)gk =
                        *(const unsigned long long*)(gate_p + (size_t)(2 * w + gr) * 2048 + col * 16 + g * 4);
                }
                #pragma unroll
                for (int r = 0; r < 4; ++r) {
                    float v = c2[gr][r] + b2v;
                    if (GATE) v *= bf2f(gk[r]);
                    outb[(size_t)(s0 + gr * 16 + g * 4 + r) * 128 + col] = f2bf(v);
                }
            }
        }
    }
}

// ---------------------------------------------------------------------------
// attention: one wave per query; qpos/vposg bf16, feat f32. (unchanged)
// ---------------------------------------------------------------------------
__global__ __launch_bounds__(256) void attn_kernel(
    const float* __restrict__ ref_pts,
    const unsigned short* __restrict__ qpos,
    const unsigned short* __restrict__ vposg,
    const float* __restrict__ ctr_feat,
    float* __restrict__ out)
{
    const int lane = threadIdx.x & 63;
    const int qi   = blockIdx.x * 4 + (threadIdx.x >> 6);

    const int   b = (int)ref_pts[qi * 3 + 0];
    const float x = ref_pts[qi * 3 + 1];
    const float y = ref_pts[qi * 3 + 2];
    const int xi = (int)(floorf(x / 0.2f) * 0.5f + 128.0f);
    const int yi = (int)(floorf(y / 0.2f) * 0.5f + 128.0f);

    const unsigned qp = *(const unsigned*)(qpos + (size_t)qi * 128 + lane * 2);
    const float qx = bf2f((unsigned short)(qp & 0xffffu));
    const float qy = bf2f((unsigned short)(qp >> 16));

    float  sc[9];
    float2 fv[9];
    #pragma unroll
    for (int n = 0; n < 9; ++n) {
        const int nx = xi + n / 3 - 1;
        const int ny = yi + n % 3 - 1;
        const bool valid = ((unsigned)nx < 256u) && ((unsigned)ny < 256u);
        float  s = 0.f;
        float2 f = {0.f, 0.f};
        if (valid) {
            const int idx = (b << 16) + (nx << 8) + ny;
            const unsigned vp = *(const unsigned*)(vposg + (size_t)idx * 128 + lane * 2);
            f = *(const float2*)(ctr_feat + (size_t)idx * 128 + lane * 2);
            s = qx * bf2f((unsigned short)(vp & 0xffffu)) + qy * bf2f((unsigned short)(vp >> 16));
        }
        sc[n] = s;
        fv[n] = f;
    }

    #pragma unroll
    for (int off = 32; off > 0; off >>= 1) {
        #pragma unroll
        for (int n = 0; n < 9; ++n)
            sc[n] += __shfl_xor(sc[n], off, 64);
    }

    float m = -1e30f;
    #pragma unroll
    for (int n = 0; n < 9; ++n) {
        sc[n] *= SCALE_INV_SQRT_D;
        m = fmaxf(m, sc[n]);
    }
    float e[9], denom = 0.f;
    #pragma unroll
    for (int n = 0; n < 9; ++n) {
        e[n] = __expf(sc[n] - m);
        denom += e[n];
    }
    const float inv = 1.0f / denom;

    float2 o = {0.f, 0.f};
    #pragma unroll
    for (int n = 0; n < 9; ++n) {
        const float w = e[n] * inv;
        o.x += w * fv[n].x;
        o.y += w * fv[n].y;
    }
    *(float2*)(out + (size_t)qi * 128 + lane * 2) = o;
}

extern "C" void kernel_launch(void* const* d_in, const int* in_sizes, int n_in,
                              void* d_out, int out_size, void* d_ws, size_t ws_size,
                              hipStream_t stream) {
    const float* ref_pts  = (const float*)d_in[0];
    const int*   ctr_coor = (const int*)d_in[1];
    const float* ctr_feat = (const float*)d_in[2];
    const float* q_w1 = (const float*)d_in[3];
    const float* q_b1 = (const float*)d_in[4];
    const float* q_w2 = (const float*)d_in[5];
    const float* q_b2 = (const float*)d_in[6];
    const float* v_w1 = (const float*)d_in[7];
    const float* v_b1 = (const float*)d_in[8];
    const float* v_w2 = (const float*)d_in[9];
    const float* v_b2 = (const float*)d_in[10];
    const float* se_wr = (const float*)d_in[11];
    const float* se_br = (const float*)d_in[12];
    const float* se_we = (const float*)d_in[13];
    const float* se_be = (const float*)d_in[14];

    unsigned short* wbuf   = (unsigned short*)d_ws;                  // 163840
    unsigned short* vposg  = wbuf + 163840;                          // NV*128 bf16
    unsigned short* qposb  = vposg + (size_t)NV * 128;               // NQ*128 bf16
    unsigned short* gate_p = qposb + (size_t)NQ * 128;               // NV*128 bf16

    const unsigned short* qw1t   = wbuf;
    const unsigned short* qw2tp  = wbuf + 32768;
    const unsigned short* vw1t   = wbuf + 65536;
    const unsigned short* vw2tp  = wbuf + 98304;
    const unsigned short* sewrt  = wbuf + 131072;
    const unsigned short* sewetp = wbuf + 147456;

    prep_kernel<<<640, 256, 0, stream>>>(q_w1, q_w2, v_w1, v_w2, se_wr, se_we, wbuf);

    se_gate_kernel<<<512, 512, 0, stream>>>(
        ctr_feat, sewrt, se_br, sewetp, se_be, gate_p);

    pe_mlp_kernel<false><<<256, 512, 0, stream>>>(
        ref_pts, nullptr, qw1t, q_b1, qw2tp, q_b2, nullptr, qposb, NQ / 32);

    pe_mlp_kernel<true><<<256, 512, 0, stream>>>(
        nullptr, ctr_coor, vw1t, v_b1, vw2tp, v_b2, gate_p, vposg, NV / 32);

    attn_kernel<<<NQ / 4, 256, 0, stream>>>(
        ref_pts, qposb, vposg, ctr_feat, (float*)d_out);
}